// Round 1
// 8976.676 us; speedup vs baseline: 2.0375x; 2.0375x over previous
//
#include <hip/hip_runtime.h>
#include <cmath>

#define B_    8192
#define V_    101
#define T_    30
#define C_    4
#define D_    64
#define HID_  128

typedef __attribute__((ext_vector_type(8))) short  short8;
typedef __attribute__((ext_vector_type(4))) float  f32x4;

#define MFMA16(a, b, c) __builtin_amdgcn_mfma_f32_16x16x32_bf16((a), (b), (c), 0, 0, 0)

// ---------------- LDS layout (ushort units, total 76288 ush = 152576 B) ----
// All bf16 tile strides are multiples of 8 with (stride/8) odd.
#define WZT_OFF   0        // [64][168] bf16 Wz^T (k' reorder), resident
#define WRT_OFF   10752    // [64][168] bf16 Wr^T, resident
#define WWT_OFF   21504    // [64][168] bf16 Ww^T, resident
#define CA_OFF    32256    // [128][168] bf16 cat: k 0..63 f, 64..127 h, 128..131 xt, 132..159 zero
#define GRH_OFF   53760    // [128][72]  bf16: g (P4->P5), then r*h (P6->P7)
#define F1T_OFF   62976    // [64][136]  bf16 f1^T (P3->P4)
#define XBT_OFF   71680    // [16][136]  bf16 xt^T (rows c 0..3, rest zero)
#define YF_OFF    36928    // FLOAT offset: y [128][5] (stride 5 -> conflict-free)
#define W1F_OFF   37568    // FLOAT offset: W1[256], b1[64], b2[64], bz[64], br[64], bw[64]
#define LDS_USH   76288

__device__ __forceinline__ unsigned short f2b(float f) {
    unsigned u = __float_as_uint(f);
    u += 0x7fffu + ((u >> 16) & 1u);          // round-to-nearest-even
    return (unsigned short)(u >> 16);
}
__device__ __forceinline__ float b2f(unsigned short h) {
    return __uint_as_float(((unsigned)h) << 16);
}
// fast transcendentals: v_exp_f32 computes 2^x; v_rcp_f32 ~1ulp.
// tanh(x) = 1 - 2/(exp2(2x*log2e)+1): x->+inf => 1, x->-inf => -1 (no NaN).
__device__ __forceinline__ float fast_tanh(float x) {
    float s = __builtin_amdgcn_exp2f(2.885390081777926817f * x);
    return 1.f - 2.f * __builtin_amdgcn_rcpf(s + 1.f);
}
// sigmoid(x) = 1/(1+exp2(-x*log2e)): x->-inf => 0, x->+inf => 1.
__device__ __forceinline__ float fast_sigmoid(float x) {
    return __builtin_amdgcn_rcpf(1.f + __builtin_amdgcn_exp2f(-1.4426950408889634f * x));
}

// ---------------- kernel 0: build bf16 images in workspace -----------------
__global__ void build_images(const float* __restrict__ dyn,
                             const float* __restrict__ Wz, const float* __restrict__ Wr,
                             const float* __restrict__ Ww, const float* __restrict__ W2,
                             unsigned short* __restrict__ dimg,
                             unsigned short* __restrict__ zimg,
                             unsigned short* __restrict__ rimg,
                             unsigned short* __restrict__ wimg,
                             unsigned short* __restrict__ w2img)
{
    int tid = blockIdx.x * blockDim.x + threadIdx.x;
    int nth = gridDim.x * blockDim.x;
    for (int i = tid; i < 128 * 136; i += nth) {
        int u = i / 136, v = i - u * 136;
        dimg[i] = (u < V_ && v < V_) ? f2b(dyn[u * V_ + v]) : (unsigned short)0;
    }
    // gate weights: transposed [n][k'] with k' reorder: 0..127 <- rows k'+4 (f,h), 128..131 <- rows 0..3 (xt)
    for (int i = tid; i < 64 * 168; i += nth) {
        int n = i / 168, k = i - n * 168;
        unsigned short vz = 0, vr = 0, vw = 0;
        if (k < 132) {
            int gk = (k < 128) ? (k + 4) : (k - 128);
            vz = f2b(Wz[gk * 64 + n]);
            vr = f2b(Wr[gk * 64 + n]);
            vw = f2b(Ww[gk * 64 + n]);
        }
        zimg[i] = vz; rimg[i] = vr; wimg[i] = vw;
    }
    for (int i = tid; i < 64 * 72; i += nth) {
        int n = i / 72, k = i - n * 72;
        w2img[i] = (k < 64) ? f2b(W2[k * 64 + n]) : (unsigned short)0;
    }
}

// ---------------- kernel 1: fused recurrent MFMA kernel --------------------
__global__ void __launch_bounds__(1024, 4)
mgcgru_mfma(const float* __restrict__ x,
            const unsigned short* __restrict__ dimg,
            const unsigned short* __restrict__ zimg,
            const unsigned short* __restrict__ rimg,
            const unsigned short* __restrict__ wimg,
            const unsigned short* __restrict__ w2img,
            const float* __restrict__ W1, const float* __restrict__ b1,
            const float* __restrict__ b2, const float* __restrict__ bz,
            const float* __restrict__ br, const float* __restrict__ bw,
            const float* __restrict__ Wf1, const float* __restrict__ bf1,
            const float* __restrict__ Wf2, const float* __restrict__ bf2,
            unsigned short* __restrict__ wsflat,
            float* __restrict__ out, int mode)
{
    extern __shared__ unsigned short sm[];
    float* smf = (float*)sm;
    const int tid  = threadIdx.x;
    const int b    = blockIdx.x;
    const int wv   = tid >> 6;
    const int lane = tid & 63;
    const int l16  = lane & 15;
    const int quad = lane >> 4;
    const int mt   = wv & 7;                 // M-tile (rows mt*16..mt*16+15)
    const int nt0  = (wv >> 3) * 2;          // owns N-tiles nt0, nt0+1

    // ---- init: zero LDS, copy resident weight images, fp32 params ----
    {
        unsigned* p = (unsigned*)sm;
        for (int i = tid; i < LDS_USH / 2; i += 1024) p[i] = 0u;
    }
    __syncthreads();
    for (int i = tid; i < 1344; i += 1024) {
        ((uint4*)&sm[WZT_OFF])[i] = ((const uint4*)zimg)[i];
        ((uint4*)&sm[WRT_OFF])[i] = ((const uint4*)rimg)[i];
        ((uint4*)&sm[WWT_OFF])[i] = ((const uint4*)wimg)[i];
    }
    for (int i = tid; i < 576; i += 1024) {
        float v;
        if      (i < 256) v = W1[i];
        else if (i < 320) v = b1[i - 256];
        else if (i < 384) v = b2[i - 320];
        else if (i < 448) v = bz[i - 384];
        else if (i < 512) v = br[i - 448];
        else              v = bw[i - 512];
        smf[W1F_OFF + i] = v;
    }

    // ---- register-resident fragments (loop-invariant) ----
    // dyn A-fragments for this wave's M-tile (used in P2 and P4): 16 VGPRs
    short8 dynf[4];
    {
        const int r = mt * 16 + l16;
        #pragma unroll
        for (int kt = 0; kt < 4; ++kt)
            dynf[kt] = *(const short8*)(dimg + r * 136 + kt * 32 + quad * 8);
    }
    // W2^T B-fragments for this wave's two N-tiles (used in P5): 16 VGPRs
    short8 w2f[2][2];
    #pragma unroll
    for (int n = 0; n < 2; ++n)
        #pragma unroll
        for (int kt = 0; kt < 2; ++kt)
            w2f[n][kt] = *(const short8*)(w2img + ((nt0 + n) * 16 + l16) * 72 + kt * 32 + quad * 8);

    float hreg[2][4] = {{0.f,0.f,0.f,0.f},{0.f,0.f,0.f,0.f}};
    float zreg[2][4];
    __syncthreads();

    const float* xb = x + (size_t)b * (V_ * T_ * C_);

    for (int t = 0; t < T_; ++t) {
        // ---- P1: xt -> CA cols 128..131 and XBT ----
        if (tid < V_ * C_) {
            int v = tid >> 2, c = tid & 3;
            unsigned short h16 = f2b(xb[v * (T_ * C_) + t * C_ + c]);
            sm[CA_OFF + v * 168 + 128 + c] = h16;
            sm[XBT_OFF + c * 136 + v]      = h16;
        }
        __syncthreads();

        // ---- P2: y = dyn @ xt  (waves 0..7; dyn A-frags from registers) ----
        if (wv < 8) {
            f32x4 acc = {0.f, 0.f, 0.f, 0.f};
            #pragma unroll
            for (int kt = 0; kt < 4; ++kt) {
                short8 bb = *(const short8*)&sm[XBT_OFF + l16*136 + kt*32 + quad*8];
                acc = MFMA16(dynf[kt], bb, acc);
            }
            if (l16 < 4) {
                #pragma unroll
                for (int e = 0; e < 4; ++e)
                    smf[YF_OFF + (wv*16 + quad*4 + e) * 5 + l16] = acc[e];
            }
        }
        __syncthreads();

        // ---- P3: f1 = tanh(y@W1 + b1) -> F1T (transposed [d][v]) ----
        {
            int u = tid & 127, db = (tid >> 7) * 8;
            float y0 = smf[YF_OFF + u*5 + 0], y1 = smf[YF_OFF + u*5 + 1];
            float y2 = smf[YF_OFF + u*5 + 2], y3 = smf[YF_OFF + u*5 + 3];
            #pragma unroll
            for (int j = 0; j < 8; ++j) {
                int d = db + j;
                float acc = smf[W1F_OFF + 256 + d]
                          + y0 * smf[W1F_OFF + 0*64 + d] + y1 * smf[W1F_OFF + 1*64 + d]
                          + y2 * smf[W1F_OFF + 2*64 + d] + y3 * smf[W1F_OFF + 3*64 + d];
                sm[F1T_OFF + d * 136 + u] = f2b(fast_tanh(acc));
            }
        }
        __syncthreads();

        // ---- P4: g = dyn @ f1 -> GRH (dyn A-frags from registers) ----
        {
            f32x4 a0 = {0.f,0.f,0.f,0.f}, a1 = {0.f,0.f,0.f,0.f};
            #pragma unroll
            for (int kt = 0; kt < 4; ++kt) {
                short8 bA = *(const short8*)&sm[F1T_OFF + (nt0*16 + l16)*136 + kt*32 + quad*8];
                short8 bB = *(const short8*)&sm[F1T_OFF + ((nt0+1)*16 + l16)*136 + kt*32 + quad*8];
                a0 = MFMA16(dynf[kt], bA, a0);
                a1 = MFMA16(dynf[kt], bB, a1);
            }
            #pragma unroll
            for (int e = 0; e < 4; ++e) {
                int row = mt*16 + quad*4 + e;
                sm[GRH_OFF + row*72 + nt0*16 + l16]     = f2b(a0[e]);
                sm[GRH_OFF + row*72 + (nt0+1)*16 + l16] = f2b(a1[e]);
            }
        }
        __syncthreads();

        // ---- P5: f = tanh(g@W2 + b2) -> CA cols 0..63 (W2 frags in regs) ----
        {
            f32x4 a0 = {0.f,0.f,0.f,0.f}, a1 = {0.f,0.f,0.f,0.f};
            #pragma unroll
            for (int kt = 0; kt < 2; ++kt) {
                short8 a = *(const short8*)&sm[GRH_OFF + (mt*16 + l16)*72 + kt*32 + quad*8];
                a0 = MFMA16(a, w2f[0][kt], a0);
                a1 = MFMA16(a, w2f[1][kt], a1);
            }
            #pragma unroll
            for (int e = 0; e < 4; ++e) {
                int row = mt*16 + quad*4 + e;
                int c0 = nt0*16 + l16, c1 = c0 + 16;
                sm[CA_OFF + row*168 + c0] = f2b(fast_tanh(a0[e] + smf[W1F_OFF + 320 + c0]));
                sm[CA_OFF + row*168 + c1] = f2b(fast_tanh(a1[e] + smf[W1F_OFF + 320 + c1]));
            }
        }
        __syncthreads();

        // ---- P6: z = sigmoid(cat@Wz+bz) (regs); r = sigmoid(cat@Wr+br);
        //          r*h -> GRH.  Shared CA A-frags, resident weights. ----
        {
            f32x4 z0 = {0.f,0.f,0.f,0.f}, z1 = {0.f,0.f,0.f,0.f};
            f32x4 r0a = {0.f,0.f,0.f,0.f}, r1a = {0.f,0.f,0.f,0.f};
            #pragma unroll
            for (int kt = 0; kt < 5; ++kt) {
                short8 a   = *(const short8*)&sm[CA_OFF + (mt*16 + l16)*168 + kt*32 + quad*8];
                short8 bz0 = *(const short8*)&sm[WZT_OFF + (nt0*16 + l16)*168 + kt*32 + quad*8];
                short8 bz1 = *(const short8*)&sm[WZT_OFF + ((nt0+1)*16 + l16)*168 + kt*32 + quad*8];
                short8 br0 = *(const short8*)&sm[WRT_OFF + (nt0*16 + l16)*168 + kt*32 + quad*8];
                short8 br1 = *(const short8*)&sm[WRT_OFF + ((nt0+1)*16 + l16)*168 + kt*32 + quad*8];
                z0  = MFMA16(a, bz0, z0);
                z1  = MFMA16(a, bz1, z1);
                r0a = MFMA16(a, br0, r0a);
                r1a = MFMA16(a, br1, r1a);
            }
            #pragma unroll
            for (int e = 0; e < 4; ++e) {
                int row = mt*16 + quad*4 + e;
                int c0 = nt0*16 + l16, c1 = c0 + 16;
                zreg[0][e] = fast_sigmoid(z0[e] + smf[W1F_OFF + 384 + c0]);
                zreg[1][e] = fast_sigmoid(z1[e] + smf[W1F_OFF + 384 + c1]);
                float r0 = fast_sigmoid(r0a[e] + smf[W1F_OFF + 448 + c0]);
                float r1 = fast_sigmoid(r1a[e] + smf[W1F_OFF + 448 + c1]);
                sm[GRH_OFF + row*72 + c0] = f2b(r0 * hreg[0][e]);
                sm[GRH_OFF + row*72 + c1] = f2b(r1 * hreg[1][e]);
            }
        }
        __syncthreads();

        // ---- P7: cn = tanh(cat2@Ww + bw); h = h + z*(cn-h); h -> CA 64..127 ----
        {
            f32x4 a0 = {0.f,0.f,0.f,0.f}, a1 = {0.f,0.f,0.f,0.f};
            #pragma unroll
            for (int kt = 0; kt < 5; ++kt) {
                short8 a;
                if (kt < 2)
                    a = *(const short8*)&sm[CA_OFF + (mt*16 + l16)*168 + kt*32 + quad*8];
                else if (kt < 4)
                    a = *(const short8*)&sm[GRH_OFF + (mt*16 + l16)*72 + (kt-2)*32 + quad*8];
                else
                    a = *(const short8*)&sm[CA_OFF + (mt*16 + l16)*168 + 128 + quad*8];
                short8 bA = *(const short8*)&sm[WWT_OFF + (nt0*16 + l16)*168 + kt*32 + quad*8];
                short8 bB = *(const short8*)&sm[WWT_OFF + ((nt0+1)*16 + l16)*168 + kt*32 + quad*8];
                a0 = MFMA16(a, bA, a0);
                a1 = MFMA16(a, bB, a1);
            }
            #pragma unroll
            for (int e = 0; e < 4; ++e) {
                int row = mt*16 + quad*4 + e;
                int c0 = nt0*16 + l16, c1 = c0 + 16;
                float cn0 = fast_tanh(a0[e] + smf[W1F_OFF + 512 + c0]);
                float cn1 = fast_tanh(a1[e] + smf[W1F_OFF + 512 + c1]);
                float h0 = hreg[0][e] + zreg[0][e] * (cn0 - hreg[0][e]);
                float h1 = hreg[1][e] + zreg[1][e] * (cn1 - hreg[1][e]);
                hreg[0][e] = h0; hreg[1][e] = h1;
                sm[CA_OFF + row*168 + 64 + c0] = f2b(h0);
                sm[CA_OFF + row*168 + 64 + c1] = f2b(h1);
            }
        }
        __syncthreads();
    } // t loop

    if (mode == 1) {
        // write flat h (bf16) to workspace for the head GEMM
        if (tid < 808) {
            int v = tid >> 3, d8 = (tid & 7) * 8;
            uint4 val = *(const uint4*)&sm[CA_OFF + v*168 + 64 + d8];
            *(uint4*)(wsflat + (size_t)b * 6464 + v * 64 + d8) = val;
        }
    } else {
        // fallback: in-block head (slow but correct). Weight regions are dead now.
        {
            int j = tid & 127, part = tid >> 7;
            float acc = 0.f;
            int k0 = part * 808;
            for (int k = k0; k < k0 + 808; ++k) {
                int v = k >> 6, d = k & 63;
                acc += b2f(sm[CA_OFF + v*168 + 64 + d]) * Wf1[(size_t)k * 128 + j];
            }
            smf[part * 128 + j] = acc;                  // scratch in WZT region
        }
        __syncthreads();
        if (tid < 128) {
            float s = bf1[tid];
            for (int p = 0; p < 8; ++p) s += smf[p * 128 + tid];
            smf[W1F_OFF + tid] = fmaxf(s, 0.f);         // hidden (W1F dead)
        }
        __syncthreads();
        for (int i = tid; i < 128 * 101; i += 1024) smf[i] = Wf2[i];  // WZT/WRT/WWT dead
        __syncthreads();
        if (tid < V_) {
            float s = bf2[tid];
            for (int j = 0; j < 128; ++j) s += smf[W1F_OFF + j] * smf[j * 101 + tid];
            smf[W1F_OFF + 128 + tid] = s;               // logits
        }
        __syncthreads();
        if (tid < V_) {
            float m = -1e30f;
            for (int u = 0; u < V_; ++u) m = fmaxf(m, smf[W1F_OFF + 128 + u]);
            smf[W1F_OFF + 256 + tid] = expf(smf[W1F_OFF + 128 + tid] - m);
        }
        __syncthreads();
        if (tid < V_) {
            float s = 0.f;
            for (int u = 0; u < V_; ++u) s += smf[W1F_OFF + 256 + u];
            out[(size_t)b * V_ + tid] = smf[W1F_OFF + 256 + tid] / s;
        }
    }
}

// ---------------- kernel 2: A1 = relu(flat @ Wf1 + bf1) --------------------
__global__ void __launch_bounds__(256)
head1_gemm(const unsigned short* __restrict__ flat,   // [8192][6464] bf16
           const float* __restrict__ Wf1,             // [6464][128]
           const float* __restrict__ bf1,
           float* __restrict__ A1)                    // [8192][128]
{
    __shared__ __align__(16) unsigned short AT[32 * 40 + 128 * 40];
    unsigned short* BT = AT + 32 * 40;
    const int tid  = threadIdx.x;
    const int Mb   = blockIdx.x * 32;
    const int wv   = tid >> 6, lane = tid & 63;
    const int l16  = lane & 15, quad = lane >> 4;
    const int mt   = wv & 1;
    const int ntB  = (wv >> 1) * 4;
    f32x4 acc[4] = {{0.f,0.f,0.f,0.f},{0.f,0.f,0.f,0.f},{0.f,0.f,0.f,0.f},{0.f,0.f,0.f,0.f}};

    for (int kt = 0; kt < 202; ++kt) {
        uint4 av;
        if (tid < 128) {
            int row = tid >> 2, k8 = (tid & 3) * 8;
            av = *(const uint4*)(flat + (size_t)(Mb + row) * 6464 + kt * 32 + k8);
        }
        float4 bv[4];
        #pragma unroll
        for (int p = 0; p < 4; ++p) {
            int g = tid + p * 256, k = g >> 5, nq = g & 31;
            bv[p] = *(const float4*)&Wf1[(size_t)(kt * 32 + k) * 128 + nq * 4];
        }
        __syncthreads();
        if (tid < 128) {
            int row = tid >> 2, k8 = (tid & 3) * 8;
            *(uint4*)&AT[row * 40 + k8] = av;
        }
        #pragma unroll
        for (int p = 0; p < 4; ++p) {
            int g = tid + p * 256, k = g >> 5, nq = g & 31;
            BT[(nq*4 + 0) * 40 + k] = f2b(bv[p].x);
            BT[(nq*4 + 1) * 40 + k] = f2b(bv[p].y);
            BT[(nq*4 + 2) * 40 + k] = f2b(bv[p].z);
            BT[(nq*4 + 3) * 40 + k] = f2b(bv[p].w);
        }
        __syncthreads();
        short8 a = *(const short8*)&AT[(mt*16 + l16) * 40 + quad * 8];
        #pragma unroll
        for (int i = 0; i < 4; ++i) {
            short8 bb = *(const short8*)&BT[((ntB + i)*16 + l16) * 40 + quad * 8];
            acc[i] = MFMA16(a, bb, acc[i]);
        }
    }
    #pragma unroll
    for (int i = 0; i < 4; ++i)
        #pragma unroll
        for (int e = 0; e < 4; ++e) {
            int row = Mb + mt*16 + quad*4 + e;
            int col = (ntB + i)*16 + l16;
            A1[(size_t)row * 128 + col] = fmaxf(acc[i][e] + bf1[col], 0.f);
        }
}

// ---------------- kernel 3: out = softmax(A1 @ Wf2 + bf2) ------------------
__global__ void head2_softmax(const float* __restrict__ A1,
                              const float* __restrict__ Wf2,   // [128][101]
                              const float* __restrict__ bf2,
                              float* __restrict__ out)
{
    extern __shared__ float s3[];
    float* WF = s3;                 // 12928
    float* AR = s3 + 12928;         // 128
    float* LG = AR + 128;           // 104
    float* EG = LG + 104;           // 104
    const int tid = threadIdx.x;    // 128 threads
    for (int i = tid; i < 128 * 101; i += 128) WF[i] = Wf2[i];
    for (int r = 0; r < 64; ++r) {
        size_t row = (size_t)blockIdx.x * 64 + r;
        __syncthreads();
        AR[tid] = A1[row * 128 + tid];
        __syncthreads();
        if (tid < V_) {
            float s = bf2[tid];
            for (int j = 0; j < 128; ++j) s += AR[j] * WF[j * 101 + tid];
            LG[tid] = s;
        }
        __syncthreads();
        if (tid < V_) {
            float m = -1e30f;
            for (int u = 0; u < V_; ++u) m = fmaxf(m, LG[u]);
            EG[tid] = expf(LG[tid] - m);
        }
        __syncthreads();
        if (tid < V_) {
            float s = 0.f;
            for (int u = 0; u < V_; ++u) s += EG[u];
            out[row * 101 + tid] = EG[tid] / s;
        }
    }
}

extern "C" void kernel_launch(void* const* d_in, const int* in_sizes, int n_in,
                              void* d_out, int out_size, void* d_ws, size_t ws_size,
                              hipStream_t stream) {
    const float* x   = (const float*)d_in[0];
    const float* dyn = (const float*)d_in[1];
    const float* W1  = (const float*)d_in[2];
    const float* b1  = (const float*)d_in[3];
    const float* W2  = (const float*)d_in[4];
    const float* b2  = (const float*)d_in[5];
    const float* Wz  = (const float*)d_in[6];
    const float* bz  = (const float*)d_in[7];
    const float* Wr  = (const float*)d_in[8];
    const float* br  = (const float*)d_in[9];
    const float* Ww  = (const float*)d_in[10];
    const float* bw  = (const float*)d_in[11];
    const float* Wf1 = (const float*)d_in[12];
    const float* bf1 = (const float*)d_in[13];
    const float* Wf2 = (const float*)d_in[14];
    const float* bf2 = (const float*)d_in[15];
    float* out = (float*)d_out;

    const size_t FLAT_B = (size_t)B_ * 6464 * 2;          // 105,906,176
    const size_t A1_B   = (size_t)B_ * 128 * 4;           //   4,194,304
    const size_t IMG_B  = (size_t)(17408 + 3 * 10752 + 4608) * 2;  // 108,544
    int mode = (ws_size >= FLAT_B + A1_B + IMG_B) ? 1 : 0;

    char* wsc = (char*)d_ws;
    unsigned short* wsflat = nullptr;
    float* A1p = nullptr;
    unsigned short* img;
    if (mode) {
        wsflat = (unsigned short*)wsc;
        A1p    = (float*)(wsc + FLAT_B);
        img    = (unsigned short*)(wsc + FLAT_B + A1_B);
    } else {
        img    = (unsigned short*)wsc;   // needs only 108,544 B
    }
    unsigned short* dimg  = img;
    unsigned short* zimg  = dimg + 17408;
    unsigned short* rimg  = zimg + 10752;
    unsigned short* wimg  = rimg + 10752;
    unsigned short* w2img = wimg + 10752;

    build_images<<<64, 256, 0, stream>>>(dyn, Wz, Wr, Ww, W2,
                                         dimg, zimg, rimg, wimg, w2img);

    (void)hipFuncSetAttribute((const void*)mgcgru_mfma,
                              hipFuncAttributeMaxDynamicSharedMemorySize, LDS_USH * 2);
    mgcgru_mfma<<<B_, 1024, LDS_USH * 2, stream>>>(
        x, dimg, zimg, rimg, wimg, w2img,
        W1, b1, b2, bz, br, bw, Wf1, bf1, Wf2, bf2, wsflat, out, mode);

    if (mode) {
        head1_gemm<<<B_ / 32, 256, 0, stream>>>(wsflat, Wf1, bf1, A1p);
        head2_softmax<<<B_ / 64, 128, (12928 + 128 + 104 + 104) * 4, stream>>>(A1p, Wf2, bf2, out);
    }
}

// Round 2
// 5931.731 us; speedup vs baseline: 3.0834x; 1.5133x over previous
//
#include <hip/hip_runtime.h>
#include <cmath>

#define B_    8192
#define V_    101
#define T_    30
#define C_    4
#define D_    64
#define HID_  128

typedef __attribute__((ext_vector_type(8))) short  short8;
typedef __attribute__((ext_vector_type(4))) float  f32x4;

#define MFMA16(a, b, c) __builtin_amdgcn_mfma_f32_16x16x32_bf16((a), (b), (c), 0, 0, 0)

// ---------------- LDS layout (ushort units, total 77312 ush = 154624 B) ----
// All bf16 tile strides are multiples of 8 with (stride/8) odd.
#define WZT_OFF   0        // [64][168] bf16 Wz^T (k' reorder), resident
#define WRT_OFF   10752    // [64][168] bf16 Wr^T, resident
#define WWT_OFF   21504    // [64][168] bf16 Ww^T, resident
#define CA_OFF    32256    // [128][168] bf16: 0..63 f, 64..127 h, 128..135/136..143 xt parity slots, rest 0
#define GRH_OFF   53760    // [128][72]  bf16: g (P4->P5), then r*h (P6->P7); rows wave-owned
#define F1T_OFF   62976    // [64][136]  bf16 f1^T (P3->P4); cols wave-owned
#define XBT_OFF   71680    // [2][16][136] bf16 xt^T double-buffered (rows c 0..3, rest zero)
#define YF_USH    76032    // float scratch y [128][5] (rows wave-owned)
#define LDS_USH   77312
#define YFF       (YF_USH/2)

__device__ __forceinline__ unsigned short f2b(float f) {
    unsigned u = __float_as_uint(f);
    u += 0x7fffu + ((u >> 16) & 1u);          // round-to-nearest-even
    return (unsigned short)(u >> 16);
}
__device__ __forceinline__ float b2f(unsigned short h) {
    return __uint_as_float(((unsigned)h) << 16);
}
// fast transcendentals via v_exp_f32 (2^x) + v_rcp_f32.
__device__ __forceinline__ float fast_tanh(float x) {
    float s = __builtin_amdgcn_exp2f(2.885390081777926817f * x);
    return 1.f - 2.f * __builtin_amdgcn_rcpf(s + 1.f);
}
__device__ __forceinline__ float fast_sigmoid(float x) {
    return __builtin_amdgcn_rcpf(1.f + __builtin_amdgcn_exp2f(-1.4426950408889634f * x));
}
// packed f32x2 -> bf16x2 (1 VALU op instead of 2 manual RNE sequences)
__device__ __forceinline__ unsigned pk_bf16(float lo, float hi) {
    unsigned r;
    asm("v_cvt_pk_bf16_f32 %0, %1, %2" : "=v"(r) : "v"(lo), "v"(hi));
    return r;
}
// store a pair of bf16 to two (non-adjacent) LDS slots
__device__ __forceinline__ void st2_bf16(unsigned short* p0, unsigned short* p1, float a, float b) {
    unsigned pk = pk_bf16(a, b);
    *p0 = (unsigned short)pk;
    *p1 = (unsigned short)(pk >> 16);
}
// wave-local LDS producer->consumer fence (same-wave write then read)
#define FENCE() do { asm volatile("s_waitcnt lgkmcnt(0)" ::: "memory"); \
                     __builtin_amdgcn_sched_barrier(0); } while (0)

// ---------------- kernel 0: build bf16 images in workspace -----------------
__global__ void build_images(const float* __restrict__ dyn,
                             const float* __restrict__ Wz, const float* __restrict__ Wr,
                             const float* __restrict__ Ww, const float* __restrict__ W2,
                             unsigned short* __restrict__ dimg,
                             unsigned short* __restrict__ zimg,
                             unsigned short* __restrict__ rimg,
                             unsigned short* __restrict__ wimg,
                             unsigned short* __restrict__ w2img)
{
    int tid = blockIdx.x * blockDim.x + threadIdx.x;
    int nth = gridDim.x * blockDim.x;
    for (int i = tid; i < 128 * 136; i += nth) {
        int u = i / 136, v = i - u * 136;
        dimg[i] = (u < V_ && v < V_) ? f2b(dyn[u * V_ + v]) : (unsigned short)0;
    }
    // gate weights: transposed [n][k'] ; k' 0..127 <- rows k'+4 (f,h), 128..131 <- rows 0..3 (xt)
    for (int i = tid; i < 64 * 168; i += nth) {
        int n = i / 168, k = i - n * 168;
        unsigned short vz = 0, vr = 0, vw = 0;
        if (k < 132) {
            int gk = (k < 128) ? (k + 4) : (k - 128);
            vz = f2b(Wz[gk * 64 + n]);
            vr = f2b(Wr[gk * 64 + n]);
            vw = f2b(Ww[gk * 64 + n]);
        }
        zimg[i] = vz; rimg[i] = vr; wimg[i] = vw;
    }
    for (int i = tid; i < 64 * 72; i += nth) {
        int n = i / 72, k = i - n * 72;
        w2img[i] = (k < 64) ? f2b(W2[k * 64 + n]) : (unsigned short)0;
    }
}

// ---------------- kernel 1: fused recurrent MFMA kernel --------------------
// 512 threads = 8 waves; wave wv owns M-tile rows wv*16..wv*16+15 through the
// whole per-step chain (all 4 N-tiles). Cross-wave edges: F1T (the single
// __syncthreads per step) and xt (parity double-buffer, written pre-barrier).
__global__ void __launch_bounds__(512, 2)
mgcgru_mfma(const float* __restrict__ x,
            const unsigned short* __restrict__ dimg,
            const unsigned short* __restrict__ zimg,
            const unsigned short* __restrict__ rimg,
            const unsigned short* __restrict__ wimg,
            const unsigned short* __restrict__ w2img,
            const float* __restrict__ W1, const float* __restrict__ b1,
            const float* __restrict__ b2, const float* __restrict__ bz,
            const float* __restrict__ br, const float* __restrict__ bw,
            const float* __restrict__ Wf1, const float* __restrict__ bf1,
            const float* __restrict__ Wf2, const float* __restrict__ bf2,
            unsigned short* __restrict__ wsflat,
            float* __restrict__ out, int mode)
{
    extern __shared__ unsigned short sm[];
    float* smf = (float*)sm;
    const int tid  = threadIdx.x;
    const int b    = blockIdx.x;
    const int wv   = tid >> 6;               // 0..7 == mt (owned M-tile)
    const int lane = tid & 63;
    const int l16  = lane & 15;
    const int quad = lane >> 4;
    const int mt   = wv;

    // ---- init: zero LDS ----
    {
        unsigned* p = (unsigned*)sm;
        for (int i = tid; i < LDS_USH / 2; i += 512) p[i] = 0u;
    }
    __syncthreads();
    // resident gate-weight images
    for (int i = tid; i < 1344; i += 512) {
        ((uint4*)&sm[WZT_OFF])[i] = ((const uint4*)zimg)[i];
        ((uint4*)&sm[WRT_OFF])[i] = ((const uint4*)rimg)[i];
        ((uint4*)&sm[WWT_OFF])[i] = ((const uint4*)wimg)[i];
    }

    // ---- register-resident loop invariants ----
    short8 dynf[4];                          // dyn A-frags, rows mt*16..+15
    #pragma unroll
    for (int kt = 0; kt < 4; ++kt)
        dynf[kt] = *(const short8*)(dimg + (mt * 16 + l16) * 136 + kt * 32 + quad * 8);
    short8 w2f[4][2];                        // W2^T B-frags, all 4 N-tiles
    #pragma unroll
    for (int nt = 0; nt < 4; ++nt)
        #pragma unroll
        for (int kt = 0; kt < 2; ++kt)
            w2f[nt][kt] = *(const short8*)(w2img + (nt * 16 + l16) * 72 + kt * 32 + quad * 8);
    float w1r[4][4], b1r[4];                 // W1[c][l16+16k], b1[l16+16k]
    #pragma unroll
    for (int c = 0; c < 4; ++c)
        #pragma unroll
        for (int k = 0; k < 4; ++k)
            w1r[c][k] = W1[c * 64 + l16 + 16 * k];
    #pragma unroll
    for (int k = 0; k < 4; ++k) b1r[k] = b1[l16 + 16 * k];
    float b2r[4], bzr[4], brr[4], bwr[4];    // per-lane gate biases (col nt*16+l16)
    #pragma unroll
    for (int nt = 0; nt < 4; ++nt) {
        int cc = nt * 16 + l16;
        b2r[nt] = b2[cc]; bzr[nt] = bz[cc]; brr[nt] = br[cc]; bwr[nt] = bw[cc];
    }

    float hreg[4][4] = {{0.f,0.f,0.f,0.f},{0.f,0.f,0.f,0.f},{0.f,0.f,0.f,0.f},{0.f,0.f,0.f,0.f}};
    float zreg[4][4];

    // ---- xt staging: each wave loads/writes its OWN rows (wave-local) ----
    const float* xb = x + (size_t)b * (V_ * T_ * C_);
    const int  xv  = mt * 16 + (lane >> 2);
    const int  xc  = lane & 3;
    const bool xok = (xv < V_);

    // preload x(t=0) into parity slot 0 + XBT slot 0
    {
        float x0 = xok ? xb[xv * (T_ * C_) + xc] : 0.f;
        if (xok) {
            unsigned short h16 = f2b(x0);
            sm[XBT_OFF + xc * 136 + xv]     = h16;
            sm[CA_OFF + xv * 168 + 128 + xc] = h16;
        }
    }
    __syncthreads();                          // B0: zeros + weights + xt(0) visible

    float xnf = 0.f;
    for (int t = 0; t < T_; ++t) {
        const int sCur  = t & 1;
        const int sNext = sCur ^ 1;
        // prefetch x(t+1) (latency hidden under P2/P3)
        if (t < T_ - 1 && xok) xnf = xb[xv * (T_ * C_) + (t + 1) * C_ + xc];

        // ---- P2: y = dyn @ xt ; y -> YF (wave-local rows) ----
        {
            f32x4 accy = {0.f, 0.f, 0.f, 0.f};
            #pragma unroll
            for (int kt = 0; kt < 4; ++kt) {
                short8 bb = *(const short8*)&sm[XBT_OFF + sCur * 2176 + l16 * 136 + kt * 32 + quad * 8];
                accy = MFMA16(dynf[kt], bb, accy);
            }
            if (l16 < 4) {
                #pragma unroll
                for (int e = 0; e < 4; ++e)
                    smf[YFF + (mt * 16 + quad * 4 + e) * 5 + l16] = accy[e];
            }
        }
        FENCE();

        // ---- P3: f1 = tanh(y@W1 + b1) -> F1T cols mt*16..+15 (wave-owned) ----
        {
            float yv[4][4];
            #pragma unroll
            for (int e = 0; e < 4; ++e)
                #pragma unroll
                for (int c = 0; c < 4; ++c)
                    yv[e][c] = smf[YFF + (mt * 16 + quad * 4 + e) * 5 + c];
            #pragma unroll
            for (int k = 0; k < 4; ++k) {
                float fe[4];
                #pragma unroll
                for (int e = 0; e < 4; ++e)
                    fe[e] = fast_tanh(b1r[k] + yv[e][0] * w1r[0][k] + yv[e][1] * w1r[1][k]
                                              + yv[e][2] * w1r[2][k] + yv[e][3] * w1r[3][k]);
                uint2 uv;
                uv.x = pk_bf16(fe[0], fe[1]);
                uv.y = pk_bf16(fe[2], fe[3]);
                *(uint2*)&sm[F1T_OFF + (l16 + 16 * k) * 136 + mt * 16 + quad * 4] = uv;
            }
        }
        // ---- PhaseA: stage xt(t+1) into the OTHER parity slot (pre-barrier) ----
        if (t < T_ - 1 && xok) {
            unsigned short h16 = f2b(xnf);
            sm[XBT_OFF + sNext * 2176 + xc * 136 + xv]      = h16;
            sm[CA_OFF + xv * 168 + 128 + 8 * sNext + xc]    = h16;
        }
        __syncthreads();                      // B3: the ONE barrier per step (F1T + xt)

        // ---- P4: g = dyn @ f1 -> GRH rows mt (wave-local from here on) ----
        {
            f32x4 ag[4] = {{0.f,0.f,0.f,0.f},{0.f,0.f,0.f,0.f},{0.f,0.f,0.f,0.f},{0.f,0.f,0.f,0.f}};
            #pragma unroll
            for (int kt = 0; kt < 4; ++kt) {
                #pragma unroll
                for (int nt = 0; nt < 4; ++nt) {
                    short8 bb = *(const short8*)&sm[F1T_OFF + (nt * 16 + l16) * 136 + kt * 32 + quad * 8];
                    ag[nt] = MFMA16(dynf[kt], bb, ag[nt]);
                }
            }
            #pragma unroll
            for (int nt = 0; nt < 4; nt += 2)
                #pragma unroll
                for (int e = 0; e < 4; ++e) {
                    int row = mt * 16 + quad * 4 + e;
                    st2_bf16(&sm[GRH_OFF + row * 72 + nt * 16 + l16],
                             &sm[GRH_OFF + row * 72 + (nt + 1) * 16 + l16],
                             ag[nt][e], ag[nt + 1][e]);
                }
        }
        FENCE();

        // ---- P5: f = tanh(g@W2 + b2) -> CA cols 0..63 (W2 frags in regs) ----
        {
            f32x4 af[4] = {{0.f,0.f,0.f,0.f},{0.f,0.f,0.f,0.f},{0.f,0.f,0.f,0.f},{0.f,0.f,0.f,0.f}};
            #pragma unroll
            for (int kt = 0; kt < 2; ++kt) {
                short8 a = *(const short8*)&sm[GRH_OFF + (mt * 16 + l16) * 72 + kt * 32 + quad * 8];
                #pragma unroll
                for (int nt = 0; nt < 4; ++nt)
                    af[nt] = MFMA16(a, w2f[nt][kt], af[nt]);
            }
            #pragma unroll
            for (int nt = 0; nt < 4; nt += 2)
                #pragma unroll
                for (int e = 0; e < 4; ++e) {
                    int row = mt * 16 + quad * 4 + e;
                    st2_bf16(&sm[CA_OFF + row * 168 + nt * 16 + l16],
                             &sm[CA_OFF + row * 168 + (nt + 1) * 16 + l16],
                             fast_tanh(af[nt][e] + b2r[nt]),
                             fast_tanh(af[nt + 1][e] + b2r[nt + 1]));
                }
        }
        FENCE();

        // ---- P6: z, r gates; r*h -> GRH rows mt ----
        {
            f32x4 az[4] = {{0.f,0.f,0.f,0.f},{0.f,0.f,0.f,0.f},{0.f,0.f,0.f,0.f},{0.f,0.f,0.f,0.f}};
            f32x4 ar[4] = {{0.f,0.f,0.f,0.f},{0.f,0.f,0.f,0.f},{0.f,0.f,0.f,0.f},{0.f,0.f,0.f,0.f}};
            #pragma unroll
            for (int kt = 0; kt < 5; ++kt) {
                short8 a;
                if (kt < 4)
                    a = *(const short8*)&sm[CA_OFF + (mt * 16 + l16) * 168 + kt * 32 + quad * 8];
                else  // xt parity slot: cols 128+8*sCur..; stale slot hits zero weight rows
                    a = *(const short8*)&sm[CA_OFF + (mt * 16 + l16) * 168 + 128 + 8 * sCur + quad * 8];
                #pragma unroll
                for (int nt = 0; nt < 4; ++nt) {
                    short8 bzf = *(const short8*)&sm[WZT_OFF + (nt * 16 + l16) * 168 + kt * 32 + quad * 8];
                    short8 brf = *(const short8*)&sm[WRT_OFF + (nt * 16 + l16) * 168 + kt * 32 + quad * 8];
                    az[nt] = MFMA16(a, bzf, az[nt]);
                    ar[nt] = MFMA16(a, brf, ar[nt]);
                }
            }
            #pragma unroll
            for (int nt = 0; nt < 4; nt += 2)
                #pragma unroll
                for (int e = 0; e < 4; ++e) {
                    int row = mt * 16 + quad * 4 + e;
                    zreg[nt][e]     = fast_sigmoid(az[nt][e] + bzr[nt]);
                    zreg[nt + 1][e] = fast_sigmoid(az[nt + 1][e] + bzr[nt + 1]);
                    float r0 = fast_sigmoid(ar[nt][e] + brr[nt]);
                    float r1 = fast_sigmoid(ar[nt + 1][e] + brr[nt + 1]);
                    st2_bf16(&sm[GRH_OFF + row * 72 + nt * 16 + l16],
                             &sm[GRH_OFF + row * 72 + (nt + 1) * 16 + l16],
                             r0 * hreg[nt][e], r1 * hreg[nt + 1][e]);
                }
        }
        FENCE();

        // ---- P7: cn = tanh(cat2@Ww + bw); h += z*(cn-h); h -> CA cols 64..127 ----
        {
            f32x4 ac[4] = {{0.f,0.f,0.f,0.f},{0.f,0.f,0.f,0.f},{0.f,0.f,0.f,0.f},{0.f,0.f,0.f,0.f}};
            #pragma unroll
            for (int kt = 0; kt < 5; ++kt) {
                short8 a;
                if (kt < 2)
                    a = *(const short8*)&sm[CA_OFF + (mt * 16 + l16) * 168 + kt * 32 + quad * 8];
                else if (kt < 4)
                    a = *(const short8*)&sm[GRH_OFF + (mt * 16 + l16) * 72 + (kt - 2) * 32 + quad * 8];
                else
                    a = *(const short8*)&sm[CA_OFF + (mt * 16 + l16) * 168 + 128 + 8 * sCur + quad * 8];
                #pragma unroll
                for (int nt = 0; nt < 4; ++nt) {
                    short8 bwf = *(const short8*)&sm[WWT_OFF + (nt * 16 + l16) * 168 + kt * 32 + quad * 8];
                    ac[nt] = MFMA16(a, bwf, ac[nt]);
                }
            }
            #pragma unroll
            for (int nt = 0; nt < 4; nt += 2)
                #pragma unroll
                for (int e = 0; e < 4; ++e) {
                    int row = mt * 16 + quad * 4 + e;
                    float cn0 = fast_tanh(ac[nt][e] + bwr[nt]);
                    float cn1 = fast_tanh(ac[nt + 1][e] + bwr[nt + 1]);
                    float h0 = hreg[nt][e]     + zreg[nt][e]     * (cn0 - hreg[nt][e]);
                    float h1 = hreg[nt + 1][e] + zreg[nt + 1][e] * (cn1 - hreg[nt + 1][e]);
                    hreg[nt][e] = h0; hreg[nt + 1][e] = h1;
                    st2_bf16(&sm[CA_OFF + row * 168 + 64 + nt * 16 + l16],
                             &sm[CA_OFF + row * 168 + 64 + (nt + 1) * 16 + l16],
                             h0, h1);
                }
        }
        // h writes are consumed by P6(t+1), which is after B3(t+1) -> no fence needed
    } // t loop

    __syncthreads();

    if (mode == 1) {
        // write flat h (bf16) to workspace for the head GEMM
        for (int i = tid; i < 808; i += 512) {
            int v = i >> 3, d8 = (i & 7) * 8;
            *(uint4*)(wsflat + (size_t)b * 6464 + v * 64 + d8) =
                *(const uint4*)&sm[CA_OFF + v * 168 + 64 + d8];
        }
    } else {
        // fallback: in-block head (slow but correct). Weight regions are dead now.
        {
            int j = tid & 127, part = tid >> 7;       // 4 parts of 1616
            float acc = 0.f;
            int k0 = part * 1616;
            for (int k = k0; k < k0 + 1616; ++k) {
                int v = k >> 6, d = k & 63;
                acc += b2f(sm[CA_OFF + v * 168 + 64 + d]) * Wf1[(size_t)k * 128 + j];
            }
            smf[part * 128 + j] = acc;                 // scratch in WZT region
        }
        __syncthreads();
        if (tid < 128) {
            float s = bf1[tid];
            for (int p = 0; p < 4; ++p) s += smf[p * 128 + tid];
            smf[512 + tid] = fmaxf(s, 0.f);
        }
        __syncthreads();
        for (int i = tid; i < 128 * 101; i += 512) smf[1024 + i] = Wf2[i];
        __syncthreads();
        if (tid < V_) {
            float s = bf2[tid];
            for (int j = 0; j < 128; ++j) s += smf[512 + j] * smf[1024 + j * 101 + tid];
            smf[14000 + tid] = s;
        }
        __syncthreads();
        if (tid < V_) {
            float m = -1e30f;
            for (int u = 0; u < V_; ++u) m = fmaxf(m, smf[14000 + u]);
            smf[14110 + tid] = expf(smf[14000 + tid] - m);
        }
        __syncthreads();
        if (tid < V_) {
            float s = 0.f;
            for (int u = 0; u < V_; ++u) s += smf[14110 + u];
            out[(size_t)b * V_ + tid] = smf[14110 + tid] / s;
        }
    }
}

// ---------------- kernel 2: A1 = relu(flat @ Wf1 + bf1) --------------------
__global__ void __launch_bounds__(256)
head1_gemm(const unsigned short* __restrict__ flat,   // [8192][6464] bf16
           const float* __restrict__ Wf1,             // [6464][128]
           const float* __restrict__ bf1,
           float* __restrict__ A1)                    // [8192][128]
{
    __shared__ __align__(16) unsigned short AT[32 * 40 + 128 * 40];
    unsigned short* BT = AT + 32 * 40;
    const int tid  = threadIdx.x;
    const int Mb   = blockIdx.x * 32;
    const int wv   = tid >> 6, lane = tid & 63;
    const int l16  = lane & 15, quad = lane >> 4;
    const int mt   = wv & 1;
    const int ntB  = (wv >> 1) * 4;
    f32x4 acc[4] = {{0.f,0.f,0.f,0.f},{0.f,0.f,0.f,0.f},{0.f,0.f,0.f,0.f},{0.f,0.f,0.f,0.f}};

    for (int kt = 0; kt < 202; ++kt) {
        uint4 av;
        if (tid < 128) {
            int row = tid >> 2, k8 = (tid & 3) * 8;
            av = *(const uint4*)(flat + (size_t)(Mb + row) * 6464 + kt * 32 + k8);
        }
        float4 bv[4];
        #pragma unroll
        for (int p = 0; p < 4; ++p) {
            int g = tid + p * 256, k = g >> 5, nq = g & 31;
            bv[p] = *(const float4*)&Wf1[(size_t)(kt * 32 + k) * 128 + nq * 4];
        }
        __syncthreads();
        if (tid < 128) {
            int row = tid >> 2, k8 = (tid & 3) * 8;
            *(uint4*)&AT[row * 40 + k8] = av;
        }
        #pragma unroll
        for (int p = 0; p < 4; ++p) {
            int g = tid + p * 256, k = g >> 5, nq = g & 31;
            BT[(nq*4 + 0) * 40 + k] = f2b(bv[p].x);
            BT[(nq*4 + 1) * 40 + k] = f2b(bv[p].y);
            BT[(nq*4 + 2) * 40 + k] = f2b(bv[p].z);
            BT[(nq*4 + 3) * 40 + k] = f2b(bv[p].w);
        }
        __syncthreads();
        short8 a = *(const short8*)&AT[(mt*16 + l16) * 40 + quad * 8];
        #pragma unroll
        for (int i = 0; i < 4; ++i) {
            short8 bb = *(const short8*)&BT[((ntB + i)*16 + l16) * 40 + quad * 8];
            acc[i] = MFMA16(a, bb, acc[i]);
        }
    }
    #pragma unroll
    for (int i = 0; i < 4; ++i)
        #pragma unroll
        for (int e = 0; e < 4; ++e) {
            int row = Mb + mt*16 + quad*4 + e;
            int col = (ntB + i)*16 + l16;
            A1[(size_t)row * 128 + col] = fmaxf(acc[i][e] + bf1[col], 0.f);
        }
}

// ---------------- kernel 3: out = softmax(A1 @ Wf2 + bf2) ------------------
__global__ void head2_softmax(const float* __restrict__ A1,
                              const float* __restrict__ Wf2,   // [128][101]
                              const float* __restrict__ bf2,
                              float* __restrict__ out)
{
    extern __shared__ float s3[];
    float* WF = s3;                 // 12928
    float* AR = s3 + 12928;         // 128
    float* LG = AR + 128;           // 104
    float* EG = LG + 104;           // 104
    const int tid = threadIdx.x;    // 128 threads
    for (int i = tid; i < 128 * 101; i += 128) WF[i] = Wf2[i];
    for (int r = 0; r < 64; ++r) {
        size_t row = (size_t)blockIdx.x * 64 + r;
        __syncthreads();
        AR[tid] = A1[row * 128 + tid];
        __syncthreads();
        if (tid < V_) {
            float s = bf2[tid];
            for (int j = 0; j < 128; ++j) s += AR[j] * WF[j * 101 + tid];
            LG[tid] = s;
        }
        __syncthreads();
        if (tid < V_) {
            float m = -1e30f;
            for (int u = 0; u < V_; ++u) m = fmaxf(m, LG[u]);
            EG[tid] = expf(LG[tid] - m);
        }
        __syncthreads();
        if (tid < V_) {
            float s = 0.f;
            for (int u = 0; u < V_; ++u) s += EG[u];
            out[row * 101 + tid] = EG[tid] / s;
        }
    }
}

extern "C" void kernel_launch(void* const* d_in, const int* in_sizes, int n_in,
                              void* d_out, int out_size, void* d_ws, size_t ws_size,
                              hipStream_t stream) {
    const float* x   = (const float*)d_in[0];
    const float* dyn = (const float*)d_in[1];
    const float* W1  = (const float*)d_in[2];
    const float* b1  = (const float*)d_in[3];
    const float* W2  = (const float*)d_in[4];
    const float* b2  = (const float*)d_in[5];
    const float* Wz  = (const float*)d_in[6];
    const float* bz  = (const float*)d_in[7];
    const float* Wr  = (const float*)d_in[8];
    const float* br  = (const float*)d_in[9];
    const float* Ww  = (const float*)d_in[10];
    const float* bw  = (const float*)d_in[11];
    const float* Wf1 = (const float*)d_in[12];
    const float* bf1 = (const float*)d_in[13];
    const float* Wf2 = (const float*)d_in[14];
    const float* bf2 = (const float*)d_in[15];
    float* out = (float*)d_out;

    const size_t FLAT_B = (size_t)B_ * 6464 * 2;          // 105,906,176
    const size_t A1_B   = (size_t)B_ * 128 * 4;           //   4,194,304
    const size_t IMG_B  = (size_t)(17408 + 3 * 10752 + 4608) * 2;  // 108,544
    int mode = (ws_size >= FLAT_B + A1_B + IMG_B) ? 1 : 0;

    char* wsc = (char*)d_ws;
    unsigned short* wsflat = nullptr;
    float* A1p = nullptr;
    unsigned short* img;
    if (mode) {
        wsflat = (unsigned short*)wsc;
        A1p    = (float*)(wsc + FLAT_B);
        img    = (unsigned short*)(wsc + FLAT_B + A1_B);
    } else {
        img    = (unsigned short*)wsc;   // needs only 108,544 B
    }
    unsigned short* dimg  = img;
    unsigned short* zimg  = dimg + 17408;
    unsigned short* rimg  = zimg + 10752;
    unsigned short* wimg  = rimg + 10752;
    unsigned short* w2img = wimg + 10752;

    build_images<<<64, 256, 0, stream>>>(dyn, Wz, Wr, Ww, W2,
                                         dimg, zimg, rimg, wimg, w2img);

    (void)hipFuncSetAttribute((const void*)mgcgru_mfma,
                              hipFuncAttributeMaxDynamicSharedMemorySize, LDS_USH * 2);
    mgcgru_mfma<<<B_, 512, LDS_USH * 2, stream>>>(
        x, dimg, zimg, rimg, wimg, w2img,
        W1, b1, b2, bz, br, bw, Wf1, bf1, Wf2, bf2, wsflat, out, mode);

    if (mode) {
        head1_gemm<<<B_ / 32, 256, 0, stream>>>(wsflat, Wf1, bf1, A1p);
        head2_softmax<<<B_ / 64, 128, (12928 + 128 + 104 + 104) * 4, stream>>>(A1p, Wf2, bf2, out);
    }
}